// Round 2
// baseline (1782.855 us; speedup 1.0000x reference)
//
#include <hip/hip_runtime.h>
#include <stdint.h>
#include <stddef.h>

// Problem constants (from reference setup_inputs)
#define B_DIM 2048
#define FIN   4096
#define FOUT  2048
#define NITER 10
#define SMIN  1e-5f

typedef float floatx4 __attribute__((ext_vector_type(4)));
typedef short bf16x8  __attribute__((ext_vector_type(8)));

// float -> bf16 round-to-nearest-even (values here are finite, nonneg)
__device__ inline unsigned short f2bf(float f) {
    unsigned int u = __float_as_uint(f);
    u += 0x7fffu + ((u >> 16) & 1u);
    return (unsigned short)(u >> 16);
}

// async global->LDS, 16B per lane. LDS dest is wave-uniform base + lane*16B.
__device__ inline void async16(const void* g, void* l) {
    __builtin_amdgcn_global_load_lds(
        (const __attribute__((address_space(1))) void*)g,
        (__attribute__((address_space(3))) void*)l, 16, 0, 0);
}

// block(256)=4 waves row-sum reduction; result broadcast to all threads
__device__ inline float block_row_sum(float v) {
    #pragma unroll
    for (int o = 32; o > 0; o >>= 1) v += __shfl_down(v, o, 64);
    __shared__ float red[4];
    const int lane = threadIdx.x & 63, w = threadIdx.x >> 6;
    if (lane == 0) red[w] = v;
    __syncthreads();
    return red[0] + red[1] + red[2] + red[3];
}

// Wn = clip(W,1e-5) / rowsum  -> bf16, row-major (FOUT x FIN)
__global__ __launch_bounds__(256) void k_norm_w(const float* __restrict__ W,
                                                unsigned short* __restrict__ Wn) {
    const int row = blockIdx.x;
    const float4* src = (const float4*)(W + (size_t)row * FIN);
    float4 vals[4];
    float s = 0.f;
    #pragma unroll
    for (int i = 0; i < 4; ++i) {
        float4 v = src[i * 256 + threadIdx.x];
        v.x = fmaxf(v.x, SMIN); v.y = fmaxf(v.y, SMIN);
        v.z = fmaxf(v.z, SMIN); v.w = fmaxf(v.w, SMIN);
        vals[i] = v;
        s += (v.x + v.y) + (v.z + v.w);
    }
    s = block_row_sum(s);
    const float inv = 1.f / fmaxf(s, 1e-20f);
    ushort4* dst = (ushort4*)(Wn + (size_t)row * FIN);
    #pragma unroll
    for (int i = 0; i < 4; ++i) {
        float4 v = vals[i];
        ushort4 o;
        o.x = f2bf(v.x * inv); o.y = f2bf(v.y * inv);
        o.z = f2bf(v.z * inv); o.w = f2bf(v.w * inv);
        dst[i * 256 + threadIdx.x] = o;
    }
}

// xn = x / max(rowsum(|x|), eps)  fp32 (B x FIN)
__global__ __launch_bounds__(256) void k_norm_x(const float* __restrict__ x,
                                                float* __restrict__ xn) {
    const int row = blockIdx.x;
    const float4* src = (const float4*)(x + (size_t)row * FIN);
    float4 vals[4];
    float s = 0.f;
    #pragma unroll
    for (int i = 0; i < 4; ++i) {
        float4 v = src[i * 256 + threadIdx.x];
        vals[i] = v;
        s += (fabsf(v.x) + fabsf(v.y)) + (fabsf(v.z) + fabsf(v.w));
    }
    s = block_row_sum(s);
    const float inv = 1.f / fmaxf(s, 1e-20f);
    float4* dst = (float4*)(xn + (size_t)row * FIN);
    #pragma unroll
    for (int i = 0; i < 4; ++i) {
        float4 v = vals[i];
        v.x *= inv; v.y *= inv; v.z *= inv; v.w *= inv;
        dst[i * 256 + threadIdx.x] = v;
    }
}

// WnT[i][o] = Wn[o][i]  (bf16), 32x32 LDS tiles
__global__ __launch_bounds__(256) void k_transpose(const unsigned short* __restrict__ src,
                                                   unsigned short* __restrict__ dst) {
    __shared__ unsigned short tile[32][33];
    const int bi = blockIdx.x * 32;   // FIN offset
    const int bo = blockIdx.y * 32;   // FOUT offset
    const int tx = threadIdx.x, ty = threadIdx.y;  // (32, 8)
    #pragma unroll
    for (int j = 0; j < 4; ++j)
        tile[ty + j * 8][tx] = src[(size_t)(bo + ty + j * 8) * FIN + bi + tx];
    __syncthreads();
    #pragma unroll
    for (int j = 0; j < 4; ++j)
        dst[(size_t)(bi + ty + j * 8) * FOUT + bo + tx] = tile[tx][ty + j * 8];
}

// h0 = 1/FOUT (exact in bf16), fp32 master + bf16 copy
__global__ __launch_bounds__(256) void k_init_h(float* __restrict__ h,
                                                unsigned short* __restrict__ hb) {
    const int i = blockIdx.x * blockDim.x + threadIdx.x;
    const float hv = 1.f / (float)FOUT;
    float4 v; v.x = hv; v.y = hv; v.z = hv; v.w = hv;
    ((float4*)h)[i] = v;
    const unsigned short b = f2bf(hv);
    ushort4 u; u.x = b; u.y = b; u.z = b; u.w = b;
    ((ushort4*)hb)[i] = u;
}

// NT GEMM: C(MxN fp32, ldc=N) = A(MxK bf16 row-major) * B(NxK bf16 row-major)^T
// 128x128 block tile, 4 waves, each wave 64x64 = 4x4 of 16x16x32 bf16 MFMA.
// m97-style: global_load_lds width=16 staging, 2-barrier K-loop, BK=32.
__global__ __launch_bounds__(256) void k_gemm_nt(const unsigned short* __restrict__ A,
                                                 const unsigned short* __restrict__ Bm,
                                                 float* __restrict__ C,
                                                 int N, int K) {
    __shared__ __align__(16) unsigned short As[128 * 32];  // 4096 shorts
    __shared__ __align__(16) unsigned short Bs[128 * 32];
    const int tid  = threadIdx.x;
    const int wave = tid >> 6;
    const int lane = tid & 63;
    const int bm = blockIdx.y * 128;
    const int bn = blockIdx.x * 128;
    const int wr = (wave >> 1) * 64;   // wave m-offset in tile
    const int wc = (wave & 1) * 64;    // wave n-offset in tile
    const int r16 = lane & 15;
    const int q   = lane >> 4;

    floatx4 acc[4][4] = {};

    // staging: wave w loads rows [w*32, w*32+32) of each 128x32 tile,
    // 2 chunks of 16 rows; lane covers row=lane>>2, k-slice=(lane&3)*8 shorts.
    // LDS short-offset for lane within chunk: (lane>>2)*32 + (lane&3)*8 == lane*8,
    // i.e. chunk base + lane*16B — matches global_load_lds semantics.
    const unsigned short* ga = A  + (size_t)(bm + wave * 32 + (lane >> 2)) * K + (lane & 3) * 8;
    const unsigned short* gb = Bm + (size_t)(bn + wave * 32 + (lane >> 2)) * K + (lane & 3) * 8;

    for (int k0 = 0; k0 < K; k0 += 32) {
        __syncthreads();   // previous iteration's ds_reads done before overwrite
        #pragma unroll
        for (int j = 0; j < 2; ++j) {
            // wave slab = 32 rows * 32 shorts = 1024 shorts; chunk = 16 rows = 512 shorts
            async16(ga + (size_t)j * 16 * K + k0, &As[wave * 1024 + j * 512]);
            async16(gb + (size_t)j * 16 * K + k0, &Bs[wave * 1024 + j * 512]);
        }
        __syncthreads();   // drains vmcnt: LDS tiles valid

        bf16x8 af[4], bfr[4];
        #pragma unroll
        for (int t = 0; t < 4; ++t) {
            af[t]  = *(const bf16x8*)&As[(wr + t * 16 + r16) * 32 + q * 8];
            bfr[t] = *(const bf16x8*)&Bs[(wc + t * 16 + r16) * 32 + q * 8];
        }
        #pragma unroll
        for (int mt = 0; mt < 4; ++mt)
            #pragma unroll
            for (int nt = 0; nt < 4; ++nt)
                acc[mt][nt] = __builtin_amdgcn_mfma_f32_16x16x32_bf16(
                    af[mt], bfr[nt], acc[mt][nt], 0, 0, 0);
    }

    // C/D layout: col = lane&15, row = (lane>>4)*4 + reg
    #pragma unroll
    for (int mt = 0; mt < 4; ++mt) {
        #pragma unroll
        for (int j = 0; j < 4; ++j) {
            float* crow = C + (size_t)(bm + wr + mt * 16 + q * 4 + j) * N + bn + wc;
            #pragma unroll
            for (int nt = 0; nt < 4; ++nt)
                crow[nt * 16 + r16] = acc[mt][nt][j];
        }
    }
}

// s = rowsum(clip(recon,1e-5)); r = xn * s / clip(recon,1e-5)  -> bf16
__global__ __launch_bounds__(256) void k_make_ratio(const float* __restrict__ recon,
                                                    const float* __restrict__ xn,
                                                    unsigned short* __restrict__ r) {
    const int row = blockIdx.x;
    const float4* rp = (const float4*)(recon + (size_t)row * FIN);
    const float4* xp = (const float4*)(xn + (size_t)row * FIN);
    float4 vals[4];
    float s = 0.f;
    #pragma unroll
    for (int i = 0; i < 4; ++i) {
        float4 v = rp[i * 256 + threadIdx.x];
        v.x = fmaxf(v.x, SMIN); v.y = fmaxf(v.y, SMIN);
        v.z = fmaxf(v.z, SMIN); v.w = fmaxf(v.w, SMIN);
        vals[i] = v;
        s += (v.x + v.y) + (v.z + v.w);
    }
    s = block_row_sum(s);
    ushort4* op = (ushort4*)(r + (size_t)row * FIN);
    #pragma unroll
    for (int i = 0; i < 4; ++i) {
        float4 x4 = xp[i * 256 + threadIdx.x];
        float4 v = vals[i];
        ushort4 o;
        o.x = f2bf(x4.x * s / v.x);
        o.y = f2bf(x4.y * s / v.y);
        o.z = f2bf(x4.z * s / v.z);
        o.w = f2bf(x4.w * s / v.w);
        op[i * 256 + threadIdx.x] = o;
    }
}

// t = clip(h*upd,1e-5); h' = t / rowsum(t); write fp32 + bf16
__global__ __launch_bounds__(256) void k_update_h(const float* __restrict__ hin,
                                                  const float* __restrict__ upd,
                                                  float* __restrict__ hout,
                                                  unsigned short* __restrict__ hbf) {
    const int row = blockIdx.x;
    const float4* hp = (const float4*)(hin + (size_t)row * FOUT);
    const float4* up = (const float4*)(upd + (size_t)row * FOUT);
    float4 vals[2];
    float s = 0.f;
    #pragma unroll
    for (int i = 0; i < 2; ++i) {
        float4 hv = hp[i * 256 + threadIdx.x];
        float4 uv = up[i * 256 + threadIdx.x];
        float4 v;
        v.x = fmaxf(hv.x * uv.x, SMIN);
        v.y = fmaxf(hv.y * uv.y, SMIN);
        v.z = fmaxf(hv.z * uv.z, SMIN);
        v.w = fmaxf(hv.w * uv.w, SMIN);
        vals[i] = v;
        s += (v.x + v.y) + (v.z + v.w);
    }
    s = block_row_sum(s);
    const float inv = 1.f / fmaxf(s, 1e-20f);
    float4* op = (float4*)(hout + (size_t)row * FOUT);
    ushort4* bp = (ushort4*)(hbf + (size_t)row * FOUT);
    #pragma unroll
    for (int i = 0; i < 2; ++i) {
        float4 v = vals[i];
        v.x *= inv; v.y *= inv; v.z *= inv; v.w *= inv;
        op[i * 256 + threadIdx.x] = v;
        ushort4 o;
        o.x = f2bf(v.x); o.y = f2bf(v.y); o.z = f2bf(v.z); o.w = f2bf(v.w);
        bp[i * 256 + threadIdx.x] = o;
    }
}

extern "C" void kernel_launch(void* const* d_in, const int* in_sizes, int n_in,
                              void* d_out, int out_size, void* d_ws, size_t ws_size,
                              hipStream_t stream) {
    const float* x = (const float*)d_in[0];   // (B, FIN)
    const float* W = (const float*)d_in[1];   // (FOUT, FIN)
    float* out = (float*)d_out;               // (B, FOUT)

    // workspace carve-out (~152 MB total)
    char* ws = (char*)d_ws;
    size_t off = 0;
    auto alloc = [&](size_t bytes) {
        void* p = ws + off;
        off += (bytes + 255) & ~(size_t)255;
        return p;
    };
    unsigned short* Wn  = (unsigned short*)alloc((size_t)FOUT * FIN * 2);  // 16MB
    unsigned short* WnT = (unsigned short*)alloc((size_t)FIN * FOUT * 2);  // 16MB
    unsigned short* hbf = (unsigned short*)alloc((size_t)B_DIM * FOUT * 2);// 8MB
    unsigned short* rbf = (unsigned short*)alloc((size_t)B_DIM * FIN * 2); // 16MB
    float* xn    = (float*)alloc((size_t)B_DIM * FIN * 4);   // 32MB
    float* h     = (float*)alloc((size_t)B_DIM * FOUT * 4);  // 16MB
    float* recon = (float*)alloc((size_t)B_DIM * FIN * 4);   // 32MB
    float* upd   = (float*)alloc((size_t)B_DIM * FOUT * 4);  // 16MB
    (void)ws_size; (void)in_sizes; (void)n_in; (void)out_size;

    // one-time prep (per launch)
    k_norm_w<<<FOUT, 256, 0, stream>>>(W, Wn);
    k_transpose<<<dim3(FIN / 32, FOUT / 32), dim3(32, 8), 0, stream>>>(Wn, WnT);
    k_norm_x<<<B_DIM, 256, 0, stream>>>(x, xn);
    k_init_h<<<(B_DIM * FOUT) / (256 * 4), 256, 0, stream>>>(h, hbf);

    for (int it = 0; it < NITER; ++it) {
        // recon(B x FIN) = h(B x FOUT) @ Wn  == NT: A=hbf (K=FOUT), B=WnT (FIN x FOUT)
        k_gemm_nt<<<dim3(FIN / 128, B_DIM / 128), 256, 0, stream>>>(hbf, WnT, recon, FIN, FOUT);
        k_make_ratio<<<B_DIM, 256, 0, stream>>>(recon, xn, rbf);
        // upd(B x FOUT) = r(B x FIN) @ Wn^T == NT: A=rbf (K=FIN), B=Wn (FOUT x FIN)
        k_gemm_nt<<<dim3(FOUT / 128, B_DIM / 128), 256, 0, stream>>>(rbf, Wn, upd, FOUT, FIN);
        k_update_h<<<B_DIM, 256, 0, stream>>>(h, upd, (it == NITER - 1) ? out : h, hbf);
    }
}

// Round 3
// 1427.758 us; speedup vs baseline: 1.2487x; 1.2487x over previous
//
#include <hip/hip_runtime.h>
#include <stdint.h>
#include <stddef.h>

// Problem constants (from reference setup_inputs)
#define B_DIM 2048
#define FIN   4096
#define FOUT  2048
#define NITER 10
#define SMIN  1e-5f

typedef float floatx4 __attribute__((ext_vector_type(4)));
typedef short bf16x8  __attribute__((ext_vector_type(8)));

// float -> bf16 round-to-nearest-even (values here are finite, nonneg)
__device__ inline unsigned short f2bf(float f) {
    unsigned int u = __float_as_uint(f);
    u += 0x7fffu + ((u >> 16) & 1u);
    return (unsigned short)(u >> 16);
}

// async global->LDS, 16B per lane. LDS dest is wave-uniform base + lane*16B.
__device__ inline void async16(const void* g, void* l) {
    __builtin_amdgcn_global_load_lds(
        (const __attribute__((address_space(1))) void*)g,
        (__attribute__((address_space(3))) void*)l, 16, 0, 0);
}

// block(256)=4 waves row-sum reduction; result broadcast to all threads
__device__ inline float block_row_sum(float v) {
    #pragma unroll
    for (int o = 32; o > 0; o >>= 1) v += __shfl_down(v, o, 64);
    __shared__ float red[4];
    const int lane = threadIdx.x & 63, w = threadIdx.x >> 6;
    if (lane == 0) red[w] = v;
    __syncthreads();
    return red[0] + red[1] + red[2] + red[3];
}

// Wn = clip(W,1e-5) / rowsum  -> bf16, row-major (FOUT x FIN)
__global__ __launch_bounds__(256) void k_norm_w(const float* __restrict__ W,
                                                unsigned short* __restrict__ Wn) {
    const int row = blockIdx.x;
    const float4* src = (const float4*)(W + (size_t)row * FIN);
    float4 vals[4];
    float s = 0.f;
    #pragma unroll
    for (int i = 0; i < 4; ++i) {
        float4 v = src[i * 256 + threadIdx.x];
        v.x = fmaxf(v.x, SMIN); v.y = fmaxf(v.y, SMIN);
        v.z = fmaxf(v.z, SMIN); v.w = fmaxf(v.w, SMIN);
        vals[i] = v;
        s += (v.x + v.y) + (v.z + v.w);
    }
    s = block_row_sum(s);
    const float inv = 1.f / fmaxf(s, 1e-20f);
    ushort4* dst = (ushort4*)(Wn + (size_t)row * FIN);
    #pragma unroll
    for (int i = 0; i < 4; ++i) {
        float4 v = vals[i];
        ushort4 o;
        o.x = f2bf(v.x * inv); o.y = f2bf(v.y * inv);
        o.z = f2bf(v.z * inv); o.w = f2bf(v.w * inv);
        dst[i * 256 + threadIdx.x] = o;
    }
}

// xn = x / max(rowsum(|x|), eps)  fp32 (B x FIN)
__global__ __launch_bounds__(256) void k_norm_x(const float* __restrict__ x,
                                                float* __restrict__ xn) {
    const int row = blockIdx.x;
    const float4* src = (const float4*)(x + (size_t)row * FIN);
    float4 vals[4];
    float s = 0.f;
    #pragma unroll
    for (int i = 0; i < 4; ++i) {
        float4 v = src[i * 256 + threadIdx.x];
        vals[i] = v;
        s += (fabsf(v.x) + fabsf(v.y)) + (fabsf(v.z) + fabsf(v.w));
    }
    s = block_row_sum(s);
    const float inv = 1.f / fmaxf(s, 1e-20f);
    float4* dst = (float4*)(xn + (size_t)row * FIN);
    #pragma unroll
    for (int i = 0; i < 4; ++i) {
        float4 v = vals[i];
        v.x *= inv; v.y *= inv; v.z *= inv; v.w *= inv;
        dst[i * 256 + threadIdx.x] = v;
    }
}

// WnT[i][o] = Wn[o][i]  (bf16), 32x32 LDS tiles
__global__ __launch_bounds__(256) void k_transpose(const unsigned short* __restrict__ src,
                                                   unsigned short* __restrict__ dst) {
    __shared__ unsigned short tile[32][33];
    const int bi = blockIdx.x * 32;   // FIN offset
    const int bo = blockIdx.y * 32;   // FOUT offset
    const int tx = threadIdx.x, ty = threadIdx.y;  // (32, 8)
    #pragma unroll
    for (int j = 0; j < 4; ++j)
        tile[ty + j * 8][tx] = src[(size_t)(bo + ty + j * 8) * FIN + bi + tx];
    __syncthreads();
    #pragma unroll
    for (int j = 0; j < 4; ++j)
        dst[(size_t)(bi + ty + j * 8) * FOUT + bo + tx] = tile[tx][ty + j * 8];
}

// h0 = 1/FOUT (exact in bf16), fp32 master + bf16 copy
__global__ __launch_bounds__(256) void k_init_h(float* __restrict__ h,
                                                unsigned short* __restrict__ hb) {
    const int i = blockIdx.x * blockDim.x + threadIdx.x;
    const float hv = 1.f / (float)FOUT;
    float4 v; v.x = hv; v.y = hv; v.z = hv; v.w = hv;
    ((float4*)h)[i] = v;
    const unsigned short b = f2bf(hv);
    ushort4 u; u.x = b; u.y = b; u.z = b; u.w = b;
    ((ushort4*)hb)[i] = u;
}

// NT GEMM with split-K: C_z(MxN fp32) = A(M x K[z-slice]) * B^T, z = blockIdx.z.
// 128x128 block tile, 4 waves, each wave 64x64 = 4x4 of 16x16x32 bf16 MFMA.
// m97-style staging (global_load_lds width=16, 2-barrier K-loop, BK=32) with
// XOR-swizzled LDS layout: global k-chunk kc of row r lives at LDS chunk
// c = kc ^ ((r>>1)&3)  -> fragment reads touch each bank exactly 2x (free).
__global__ __launch_bounds__(256) void k_gemm_nt(const unsigned short* __restrict__ A,
                                                 const unsigned short* __restrict__ Bm,
                                                 float* __restrict__ C,
                                                 int N, int K, int Ksub) {
    __shared__ __align__(16) unsigned short As[128 * 32];  // 4096 shorts
    __shared__ __align__(16) unsigned short Bs[128 * 32];
    const int tid  = threadIdx.x;
    const int wave = tid >> 6;
    const int lane = tid & 63;
    const int bm = blockIdx.y * 128;
    const int bn = blockIdx.x * 128;
    const int kz = blockIdx.z * Ksub;
    float* Cz = C + (size_t)blockIdx.z * B_DIM * N;
    const int wr = (wave >> 1) * 64;   // wave m-offset in tile
    const int wc = (wave & 1) * 64;    // wave n-offset in tile
    const int r16 = lane & 15;
    const int q   = lane >> 4;

    floatx4 acc[4][4] = {};

    // staging: wave w loads rows [w*32, w*32+32), 2 chunks of 16 rows.
    // lane covers local row lr=lane>>2; swizzled k-chunk kc=(lane&3)^((lane>>3)&3)
    // so that LDS slot (lr, lane&3) holds chunk (lane&3)^((lr>>1)&3).
    const int ks = ((lane & 3) ^ ((lane >> 3) & 3)) * 8;   // shorts
    const unsigned short* ga = A  + (size_t)(bm + wave * 32 + (lane >> 2)) * K + ks;
    const unsigned short* gb = Bm + (size_t)(bn + wave * 32 + (lane >> 2)) * K + ks;

    for (int k0 = kz; k0 < kz + Ksub; k0 += 32) {
        __syncthreads();   // previous iteration's ds_reads done before overwrite
        #pragma unroll
        for (int j = 0; j < 2; ++j) {
            // wave slab = 32 rows * 32 shorts = 1024 shorts; chunk = 16 rows = 512
            async16(ga + (size_t)j * 16 * K + k0, &As[wave * 1024 + j * 512]);
            async16(gb + (size_t)j * 16 * K + k0, &Bs[wave * 1024 + j * 512]);
        }
        __syncthreads();   // drains vmcnt: LDS tiles valid

        // fragment read: row r = wr/wc + t*16 + r16; k-chunk q lives at
        // LDS chunk c = q ^ ((r>>1)&3); (t*16, wr, wc are multiples of 16
        // so only r16 contributes to the swizzle bits)
        const int c8 = (q ^ ((r16 >> 1) & 3)) * 8;
        bf16x8 af[4], bfr[4];
        #pragma unroll
        for (int t = 0; t < 4; ++t) {
            af[t]  = *(const bf16x8*)&As[(wr + t * 16 + r16) * 32 + c8];
            bfr[t] = *(const bf16x8*)&Bs[(wc + t * 16 + r16) * 32 + c8];
        }
        #pragma unroll
        for (int mt = 0; mt < 4; ++mt)
            #pragma unroll
            for (int nt = 0; nt < 4; ++nt)
                acc[mt][nt] = __builtin_amdgcn_mfma_f32_16x16x32_bf16(
                    af[mt], bfr[nt], acc[mt][nt], 0, 0, 0);
    }

    // C/D layout: col = lane&15, row = (lane>>4)*4 + reg
    #pragma unroll
    for (int mt = 0; mt < 4; ++mt) {
        #pragma unroll
        for (int j = 0; j < 4; ++j) {
            float* crow = Cz + (size_t)(bm + wr + mt * 16 + q * 4 + j) * N + bn + wc;
            #pragma unroll
            for (int nt = 0; nt < 4; ++nt)
                crow[nt * 16 + r16] = acc[mt][nt][j];
        }
    }
}

// recon = sum of nparts partials; s = rowsum(clip(recon,1e-5));
// r = xn * s / clip(recon,1e-5)  -> bf16
__global__ __launch_bounds__(256) void k_make_ratio(const float* __restrict__ rec,
                                                    int nparts,
                                                    const float* __restrict__ xn,
                                                    unsigned short* __restrict__ r) {
    const int row = blockIdx.x;
    const float4* xp = (const float4*)(xn + (size_t)row * FIN);
    float4 vals[4];
    float s = 0.f;
    #pragma unroll
    for (int i = 0; i < 4; ++i) {
        const int idx = i * 256 + threadIdx.x;
        float4 v = ((const float4*)(rec + (size_t)row * FIN))[idx];
        for (int z = 1; z < nparts; ++z) {
            float4 p = ((const float4*)(rec + (size_t)z * B_DIM * FIN + (size_t)row * FIN))[idx];
            v.x += p.x; v.y += p.y; v.z += p.z; v.w += p.w;
        }
        v.x = fmaxf(v.x, SMIN); v.y = fmaxf(v.y, SMIN);
        v.z = fmaxf(v.z, SMIN); v.w = fmaxf(v.w, SMIN);
        vals[i] = v;
        s += (v.x + v.y) + (v.z + v.w);
    }
    s = block_row_sum(s);
    ushort4* op = (ushort4*)(r + (size_t)row * FIN);
    #pragma unroll
    for (int i = 0; i < 4; ++i) {
        float4 x4 = xp[i * 256 + threadIdx.x];
        float4 v = vals[i];
        ushort4 o;
        o.x = f2bf(x4.x * s / v.x);
        o.y = f2bf(x4.y * s / v.y);
        o.z = f2bf(x4.z * s / v.z);
        o.w = f2bf(x4.w * s / v.w);
        op[i * 256 + threadIdx.x] = o;
    }
}

// upd = sum of nparts partials; t = clip(h*upd,1e-5); h' = t / rowsum(t)
__global__ __launch_bounds__(256) void k_update_h(const float* __restrict__ hin,
                                                  const float* __restrict__ upd,
                                                  int nparts,
                                                  float* __restrict__ hout,
                                                  unsigned short* __restrict__ hbf) {
    const int row = blockIdx.x;
    const float4* hp = (const float4*)(hin + (size_t)row * FOUT);
    float4 vals[2];
    float s = 0.f;
    #pragma unroll
    for (int i = 0; i < 2; ++i) {
        const int idx = i * 256 + threadIdx.x;
        float4 hv = hp[idx];
        float4 uv = ((const float4*)(upd + (size_t)row * FOUT))[idx];
        for (int z = 1; z < nparts; ++z) {
            float4 p = ((const float4*)(upd + (size_t)z * B_DIM * FOUT + (size_t)row * FOUT))[idx];
            uv.x += p.x; uv.y += p.y; uv.z += p.z; uv.w += p.w;
        }
        float4 v;
        v.x = fmaxf(hv.x * uv.x, SMIN);
        v.y = fmaxf(hv.y * uv.y, SMIN);
        v.z = fmaxf(hv.z * uv.z, SMIN);
        v.w = fmaxf(hv.w * uv.w, SMIN);
        vals[i] = v;
        s += (v.x + v.y) + (v.z + v.w);
    }
    s = block_row_sum(s);
    const float inv = 1.f / fmaxf(s, 1e-20f);
    float4* op = (float4*)(hout + (size_t)row * FOUT);
    ushort4* bp = (ushort4*)(hbf + (size_t)row * FOUT);
    #pragma unroll
    for (int i = 0; i < 2; ++i) {
        float4 v = vals[i];
        v.x *= inv; v.y *= inv; v.z *= inv; v.w *= inv;
        op[i * 256 + threadIdx.x] = v;
        ushort4 o;
        o.x = f2bf(v.x); o.y = f2bf(v.y); o.z = f2bf(v.z); o.w = f2bf(v.w);
        bp[i * 256 + threadIdx.x] = o;
    }
}

extern "C" void kernel_launch(void* const* d_in, const int* in_sizes, int n_in,
                              void* d_out, int out_size, void* d_ws, size_t ws_size,
                              hipStream_t stream) {
    const float* x = (const float*)d_in[0];   // (B, FIN)
    const float* W = (const float*)d_in[1];   // (FOUT, FIN)
    float* out = (float*)d_out;               // (B, FOUT)

    // split-K factors, chosen by available workspace (ws_size is launch-
    // invariant, so this branch is stable across graph capture/replay).
    const size_t RECON_PART = (size_t)B_DIM * FIN * 4;   // 33.55 MB
    const size_t UPD_PART   = (size_t)B_DIM * FOUT * 4;  // 16.78 MB
    const size_t FIXED = 109100000;                      // non-partial buffers
    int S1 = 1, S2 = 1;
    if (ws_size >= FIXED + 2 * RECON_PART + 4 * UPD_PART + (1 << 20)) {
        S1 = 2; S2 = 4;
    } else if (ws_size >= FIXED + 2 * RECON_PART + 2 * UPD_PART + (1 << 20)) {
        S1 = 2; S2 = 2;
    }

    char* ws = (char*)d_ws;
    size_t off = 0;
    auto alloc = [&](size_t bytes) {
        void* p = ws + off;
        off += (bytes + 255) & ~(size_t)255;
        return p;
    };
    unsigned short* Wn  = (unsigned short*)alloc((size_t)FOUT * FIN * 2);  // 16MB
    unsigned short* WnT = (unsigned short*)alloc((size_t)FIN * FOUT * 2);  // 16MB
    unsigned short* hbf = (unsigned short*)alloc((size_t)B_DIM * FOUT * 2);// 8MB
    unsigned short* rbf = (unsigned short*)alloc((size_t)B_DIM * FIN * 2); // 16MB
    float* xn    = (float*)alloc((size_t)B_DIM * FIN * 4);   // 32MB
    float* h     = (float*)alloc((size_t)B_DIM * FOUT * 4);  // 16MB
    float* recon = (float*)alloc(RECON_PART * S1);           // 32MB * S1
    float* upd   = (float*)alloc(UPD_PART * S2);             // 16MB * S2
    (void)in_sizes; (void)n_in; (void)out_size;

    // one-time prep (per launch)
    k_norm_w<<<FOUT, 256, 0, stream>>>(W, Wn);
    k_transpose<<<dim3(FIN / 32, FOUT / 32), dim3(32, 8), 0, stream>>>(Wn, WnT);
    k_norm_x<<<B_DIM, 256, 0, stream>>>(x, xn);
    k_init_h<<<(B_DIM * FOUT) / (256 * 4), 256, 0, stream>>>(h, hbf);

    for (int it = 0; it < NITER; ++it) {
        // recon(B x FIN) = h @ Wn  == NT: A=hbf (K=FOUT), B=WnT (FIN x FOUT)
        k_gemm_nt<<<dim3(FIN / 128, B_DIM / 128, S1), 256, 0, stream>>>(
            hbf, WnT, recon, FIN, FOUT, FOUT / S1);
        k_make_ratio<<<B_DIM, 256, 0, stream>>>(recon, S1, xn, rbf);
        // upd(B x FOUT) = r @ Wn^T == NT: A=rbf (K=FIN), B=Wn (FOUT x FIN)
        k_gemm_nt<<<dim3(FOUT / 128, B_DIM / 128, S2), 256, 0, stream>>>(
            rbf, Wn, upd, FOUT, FIN, FIN / S2);
        k_update_h<<<B_DIM, 256, 0, stream>>>(h, upd, S2, (it == NITER - 1) ? out : h, hbf);
    }
}

// Round 4
// 1288.996 us; speedup vs baseline: 1.3831x; 1.1077x over previous
//
#include <hip/hip_runtime.h>
#include <stdint.h>
#include <stddef.h>

#define B_DIM 2048
#define FIN   4096
#define FOUT  2048
#define NITER 10
#define SMIN  1e-5f

typedef float floatx16 __attribute__((ext_vector_type(16)));
typedef short bf16x8   __attribute__((ext_vector_type(8)));

__device__ inline unsigned short f2bf(float f) {
    unsigned int u = __float_as_uint(f);
    u += 0x7fffu + ((u >> 16) & 1u);
    return (unsigned short)(u >> 16);
}
__device__ inline float bflo(unsigned int u) { return __uint_as_float(u << 16); }
__device__ inline float bfhi(unsigned int u) { return __uint_as_float(u & 0xffff0000u); }
__device__ inline unsigned int pack2(float a, float b) {
    return (unsigned int)f2bf(a) | ((unsigned int)f2bf(b) << 16);
}

__device__ inline void async16(const void* g, void* l) {
    __builtin_amdgcn_global_load_lds(
        (const __attribute__((address_space(1))) void*)g,
        (__attribute__((address_space(3))) void*)l, 16, 0, 0);
}

__device__ inline float block_row_sum(float v) {
    #pragma unroll
    for (int o = 32; o > 0; o >>= 1) v += __shfl_down(v, o, 64);
    __shared__ float red[4];
    const int lane = threadIdx.x & 63, w = threadIdx.x >> 6;
    if (lane == 0) red[w] = v;
    __syncthreads();
    return red[0] + red[1] + red[2] + red[3];
}

// Wn = clip(W,1e-5)/rowsum -> bf16 (FOUT x FIN)
__global__ __launch_bounds__(256) void k_norm_w(const float* __restrict__ W,
                                                unsigned short* __restrict__ Wn) {
    const int row = blockIdx.x;
    const float4* src = (const float4*)(W + (size_t)row * FIN);
    float4 vals[4];
    float s = 0.f;
    #pragma unroll
    for (int i = 0; i < 4; ++i) {
        float4 v = src[i * 256 + threadIdx.x];
        v.x = fmaxf(v.x, SMIN); v.y = fmaxf(v.y, SMIN);
        v.z = fmaxf(v.z, SMIN); v.w = fmaxf(v.w, SMIN);
        vals[i] = v;
        s += (v.x + v.y) + (v.z + v.w);
    }
    s = block_row_sum(s);
    const float inv = 1.f / fmaxf(s, 1e-20f);
    ushort4* dst = (ushort4*)(Wn + (size_t)row * FIN);
    #pragma unroll
    for (int i = 0; i < 4; ++i) {
        float4 v = vals[i];
        ushort4 o;
        o.x = f2bf(v.x * inv); o.y = f2bf(v.y * inv);
        o.z = f2bf(v.z * inv); o.w = f2bf(v.w * inv);
        dst[i * 256 + threadIdx.x] = o;
    }
}

// xn = x / rowsum(x) -> bf16 packed (B x FIN)
__global__ __launch_bounds__(256) void k_norm_x(const float* __restrict__ x,
                                                unsigned int* __restrict__ xnb) {
    const int row = blockIdx.x;
    const float4* src = (const float4*)(x + (size_t)row * FIN);
    float4 vals[4];
    float s = 0.f;
    #pragma unroll
    for (int j = 0; j < 2; ++j) {
        const int idx = j * 256 + threadIdx.x;
        float4 a = src[2 * idx], b = src[2 * idx + 1];
        vals[2 * j] = a; vals[2 * j + 1] = b;
        s += (fabsf(a.x) + fabsf(a.y)) + (fabsf(a.z) + fabsf(a.w));
        s += (fabsf(b.x) + fabsf(b.y)) + (fabsf(b.z) + fabsf(b.w));
    }
    s = block_row_sum(s);
    const float inv = 1.f / fmaxf(s, 1e-20f);
    uint4* dst = (uint4*)(xnb + (size_t)row * (FIN / 2));
    #pragma unroll
    for (int j = 0; j < 2; ++j) {
        float4 a = vals[2 * j], b = vals[2 * j + 1];
        uint4 o;
        o.x = pack2(a.x * inv, a.y * inv);
        o.y = pack2(a.z * inv, a.w * inv);
        o.z = pack2(b.x * inv, b.y * inv);
        o.w = pack2(b.z * inv, b.w * inv);
        dst[j * 256 + threadIdx.x] = o;
    }
}

// WnT[i][o] = Wn[o][i]  (bf16)
__global__ __launch_bounds__(256) void k_transpose(const unsigned short* __restrict__ src,
                                                   unsigned short* __restrict__ dst) {
    __shared__ unsigned short tile[32][33];
    const int bi = blockIdx.x * 32, bo = blockIdx.y * 32;
    const int tx = threadIdx.x, ty = threadIdx.y;  // (32,8)
    #pragma unroll
    for (int j = 0; j < 4; ++j)
        tile[ty + j * 8][tx] = src[(size_t)(bo + ty + j * 8) * FIN + bi + tx];
    __syncthreads();
    #pragma unroll
    for (int j = 0; j < 4; ++j)
        dst[(size_t)(bi + ty + j * 8) * FOUT + bo + tx] = tile[tx][ty + j * 8];
}

__global__ __launch_bounds__(256) void k_init_h(float* __restrict__ h,
                                                unsigned short* __restrict__ hb) {
    const int i = blockIdx.x * blockDim.x + threadIdx.x;
    const float hv = 1.f / (float)FOUT;
    float4 v; v.x = hv; v.y = hv; v.z = hv; v.w = hv;
    ((float4*)h)[i] = v;
    const unsigned short b = f2bf(hv);
    ushort4 u; u.x = b; u.y = b; u.z = b; u.w = b;
    ((ushort4*)hb)[i] = u;
}

// NT GEMM, split-K, 128x128 tile, BK=64, 4 waves each 64x64 = 2x2 of
// v_mfma_f32_32x32x16_bf16. XOR-swizzled LDS (row stride 64 shorts = 128B):
// slot s at row r holds global k-chunk s^(r&7); all b128 reads are even
// 8-touches/bank. Staging: global_load_lds width=16, 2-barrier K-loop.
// OUT_BF16: write partials as bf16 (recon path) else fp32 (upd path).
template <int OUT_BF16>
__global__ __launch_bounds__(256) void k_gemm_nt(const unsigned short* __restrict__ A,
                                                 const unsigned short* __restrict__ Bm,
                                                 void* __restrict__ C,
                                                 int N, int K, int Ksub) {
    __shared__ __align__(16) unsigned short As[128 * 64];  // 16 KB
    __shared__ __align__(16) unsigned short Bs[128 * 64];  // 16 KB
    const int tid  = threadIdx.x;
    const int wave = tid >> 6;
    const int lane = tid & 63;
    const int bm = blockIdx.y * 128;
    const int bn = blockIdx.x * 128;
    const int kz = blockIdx.z * Ksub;
    const int wr = (wave >> 1) * 64;
    const int wc = (wave & 1) * 64;
    const int l31 = lane & 31;
    const int half = lane >> 5;

    floatx16 acc[2][2] = {};

    // staging: wave w loads rows [w*32,w*32+32), 4 groups of 8 rows.
    // lane -> (row lr=lane>>3, slot=lane&7); global chunk = slot^(lr&7).
    const int lr = lane >> 3;
    const int ks = ((lane & 7) ^ (lr & 7)) * 8;   // shorts
    const unsigned short* ga = A  + (size_t)(bm + wave * 32 + lr) * K + ks;
    const unsigned short* gb = Bm + (size_t)(bn + wave * 32 + lr) * K + ks;

    for (int k0 = kz; k0 < kz + Ksub; k0 += 64) {
        __syncthreads();
        #pragma unroll
        for (int j = 0; j < 4; ++j) {
            // wave slab = 32 rows * 64 shorts = 2048; 8-row group = 512 shorts
            async16(ga + (size_t)j * 8 * K + k0, &As[wave * 2048 + j * 512]);
            async16(gb + (size_t)j * 8 * K + k0, &Bs[wave * 2048 + j * 512]);
        }
        __syncthreads();

        #pragma unroll
        for (int kk = 0; kk < 4; ++kk) {
            // A/B frag: m/n = l31, k = half*8 + j (within this kk's K=16)
            // global chunk c = kk*2 + half at row r -> slot c^(r&7), r&7 = lane&7
            const int slot = ((kk * 2 + half) ^ (lane & 7)) * 8;
            bf16x8 af[2], bf[2];
            #pragma unroll
            for (int t = 0; t < 2; ++t) {
                af[t] = *(const bf16x8*)&As[(wr + t * 32 + l31) * 64 + slot];
                bf[t] = *(const bf16x8*)&Bs[(wc + t * 32 + l31) * 64 + slot];
            }
            #pragma unroll
            for (int mt = 0; mt < 2; ++mt)
                #pragma unroll
                for (int nt = 0; nt < 2; ++nt)
                    acc[mt][nt] = __builtin_amdgcn_mfma_f32_32x32x16_bf16(
                        af[mt], bf[nt], acc[mt][nt], 0, 0, 0);
        }
    }

    // C/D (verified m74/m101): col = lane&31, row = (reg&3)+8*(reg>>2)+4*(lane>>5)
    const int row0 = 4 * half;
    #pragma unroll
    for (int mt = 0; mt < 2; ++mt) {
        #pragma unroll
        for (int nt = 0; nt < 2; ++nt) {
            #pragma unroll
            for (int reg = 0; reg < 16; ++reg) {
                const int rr = bm + wr + mt * 32 + row0 + (reg & 3) + 8 * (reg >> 2);
                const int cc = bn + wc + nt * 32 + l31;
                if (OUT_BF16) {
                    unsigned short* o = (unsigned short*)C + (size_t)blockIdx.z * B_DIM * N;
                    o[(size_t)rr * N + cc] = f2bf(acc[mt][nt][reg]);
                } else {
                    float* o = (float*)C + (size_t)blockIdx.z * B_DIM * N;
                    o[(size_t)rr * N + cc] = acc[mt][nt][reg];
                }
            }
        }
    }
}

// recon = sum of bf16 partials; s = rowsum(clip); r = xn*s/clip -> bf16
__global__ __launch_bounds__(256) void k_make_ratio(const unsigned short* __restrict__ rec,
                                                    int nparts,
                                                    const unsigned int* __restrict__ xnb,
                                                    unsigned int* __restrict__ r) {
    const int row = blockIdx.x;
    float v[16];
    float s = 0.f;
    #pragma unroll
    for (int g = 0; g < 2; ++g) {
        const int idx = g * 256 + threadIdx.x;
        uint4 u = ((const uint4*)(rec + (size_t)row * FIN))[idx];
        float* p = v + g * 8;
        p[0] = bflo(u.x); p[1] = bfhi(u.x); p[2] = bflo(u.y); p[3] = bfhi(u.y);
        p[4] = bflo(u.z); p[5] = bfhi(u.z); p[6] = bflo(u.w); p[7] = bfhi(u.w);
        for (int z = 1; z < nparts; ++z) {
            uint4 q = ((const uint4*)(rec + (size_t)z * B_DIM * FIN + (size_t)row * FIN))[idx];
            p[0] += bflo(q.x); p[1] += bfhi(q.x); p[2] += bflo(q.y); p[3] += bfhi(q.y);
            p[4] += bflo(q.z); p[5] += bfhi(q.z); p[6] += bflo(q.w); p[7] += bfhi(q.w);
        }
        #pragma unroll
        for (int e = 0; e < 8; ++e) { p[e] = fmaxf(p[e], SMIN); s += p[e]; }
    }
    s = block_row_sum(s);
    #pragma unroll
    for (int g = 0; g < 2; ++g) {
        const int idx = g * 256 + threadIdx.x;
        uint4 xu = ((const uint4*)(xnb + (size_t)row * (FIN / 2)))[idx];
        float* p = v + g * 8;
        uint4 o;
        o.x = pack2(bflo(xu.x) * s / p[0], bfhi(xu.x) * s / p[1]);
        o.y = pack2(bflo(xu.y) * s / p[2], bfhi(xu.y) * s / p[3]);
        o.z = pack2(bflo(xu.z) * s / p[4], bfhi(xu.z) * s / p[5]);
        o.w = pack2(bflo(xu.w) * s / p[6], bfhi(xu.w) * s / p[7]);
        ((uint4*)(r + (size_t)row * (FIN / 2)))[idx] = o;
    }
}

// upd = sum fp32 partials; t = clip(h*upd); h' = t/rowsum(t); fp32 + bf16 out
__global__ __launch_bounds__(256) void k_update_h(const float* __restrict__ hin,
                                                  const float* __restrict__ upd,
                                                  int nparts,
                                                  float* __restrict__ hout,
                                                  unsigned short* __restrict__ hbf) {
    const int row = blockIdx.x;
    const float4* hp = (const float4*)(hin + (size_t)row * FOUT);
    float4 vals[2];
    float s = 0.f;
    #pragma unroll
    for (int i = 0; i < 2; ++i) {
        const int idx = i * 256 + threadIdx.x;
        float4 hv = hp[idx];
        float4 uv = ((const float4*)(upd + (size_t)row * FOUT))[idx];
        for (int z = 1; z < nparts; ++z) {
            float4 p = ((const float4*)(upd + (size_t)z * B_DIM * FOUT + (size_t)row * FOUT))[idx];
            uv.x += p.x; uv.y += p.y; uv.z += p.z; uv.w += p.w;
        }
        float4 v;
        v.x = fmaxf(hv.x * uv.x, SMIN);
        v.y = fmaxf(hv.y * uv.y, SMIN);
        v.z = fmaxf(hv.z * uv.z, SMIN);
        v.w = fmaxf(hv.w * uv.w, SMIN);
        vals[i] = v;
        s += (v.x + v.y) + (v.z + v.w);
    }
    s = block_row_sum(s);
    const float inv = 1.f / fmaxf(s, 1e-20f);
    float4* op = (float4*)(hout + (size_t)row * FOUT);
    ushort4* bp = (ushort4*)(hbf + (size_t)row * FOUT);
    #pragma unroll
    for (int i = 0; i < 2; ++i) {
        float4 v = vals[i];
        v.x *= inv; v.y *= inv; v.z *= inv; v.w *= inv;
        op[i * 256 + threadIdx.x] = v;
        ushort4 o;
        o.x = f2bf(v.x); o.y = f2bf(v.y); o.z = f2bf(v.z); o.w = f2bf(v.w);
        bp[i * 256 + threadIdx.x] = o;
    }
}

extern "C" void kernel_launch(void* const* d_in, const int* in_sizes, int n_in,
                              void* d_out, int out_size, void* d_ws, size_t ws_size,
                              hipStream_t stream) {
    const float* x = (const float*)d_in[0];
    const float* W = (const float*)d_in[1];
    float* out = (float*)d_out;

    const size_t RECON_PART = (size_t)B_DIM * FIN * 2;   // bf16, 16.78 MB
    const size_t UPD_PART   = (size_t)B_DIM * FOUT * 4;  // fp32, 16.78 MB
    const size_t FIXED      = 93000000;                  // non-partial buffers
    int S1 = 1, S2 = 1;
    if (ws_size >= FIXED + 2 * RECON_PART + 4 * UPD_PART + (1 << 20)) {
        S1 = 2; S2 = 4;
    }

    char* ws = (char*)d_ws;
    size_t off = 0;
    auto alloc = [&](size_t bytes) {
        void* p = ws + off;
        off += (bytes + 255) & ~(size_t)255;
        return p;
    };
    unsigned short* Wn  = (unsigned short*)alloc((size_t)FOUT * FIN * 2);
    unsigned short* WnT = (unsigned short*)alloc((size_t)FIN * FOUT * 2);
    unsigned short* hbf = (unsigned short*)alloc((size_t)B_DIM * FOUT * 2);
    unsigned int*   rbf = (unsigned int*)alloc((size_t)B_DIM * FIN * 2);
    unsigned int*   xnb = (unsigned int*)alloc((size_t)B_DIM * FIN * 2);
    float* h            = (float*)alloc((size_t)B_DIM * FOUT * 4);
    unsigned short* rec = (unsigned short*)alloc(RECON_PART * S1);
    float* upd          = (float*)alloc(UPD_PART * S2);
    (void)in_sizes; (void)n_in; (void)out_size;

    k_norm_w<<<FOUT, 256, 0, stream>>>(W, Wn);
    k_transpose<<<dim3(FIN / 32, FOUT / 32), dim3(32, 8), 0, stream>>>(Wn, WnT);
    k_norm_x<<<B_DIM, 256, 0, stream>>>(x, xnb);
    k_init_h<<<(B_DIM * FOUT) / (256 * 4), 256, 0, stream>>>(h, hbf);

    for (int it = 0; it < NITER; ++it) {
        // recon = h @ Wn : NT A=hbf (K=FOUT), B=WnT (FIN x FOUT), bf16 partials
        k_gemm_nt<1><<<dim3(FIN / 128, B_DIM / 128, S1), 256, 0, stream>>>(
            hbf, WnT, rec, FIN, FOUT, FOUT / S1);
        k_make_ratio<<<B_DIM, 256, 0, stream>>>(rec, S1, xnb, rbf);
        // upd = r @ Wn^T : NT A=rbf (K=FIN), B=Wn (FOUT x FIN), fp32 partials
        k_gemm_nt<0><<<dim3(FOUT / 128, B_DIM / 128, S2), 256, 0, stream>>>(
            (const unsigned short*)rbf, Wn, upd, FOUT, FIN, FIN / S2);
        k_update_h<<<B_DIM, 256, 0, stream>>>(h, upd, S2, (it == NITER - 1) ? out : h, hbf);
    }
}